// Round 1
// baseline (9013.876 us; speedup 1.0000x reference)
//
#include <hip/hip_runtime.h>

typedef __attribute__((ext_vector_type(8))) short short8v;
typedef __attribute__((ext_vector_type(4))) short short4v;
typedef __attribute__((ext_vector_type(4))) float f32x4;
typedef __attribute__((ext_vector_type(4))) float float4v;

#define NHID 1024
#define NCAT 1024
#define NB   64
#define NT   512
#define NWG  64

__device__ __forceinline__ short f2bf(float f) {
  union { float f; unsigned u; } c; c.f = f;
  unsigned r = (c.u + 0x7fffu + ((c.u >> 16) & 1u)) >> 16;
  return (short)r;
}

// Cast x [B,T,CATS] f32 -> bf16, and h0 [B,NH] f32 -> bf16 (initial h buffer).
__global__ void cast_kernel(const float* __restrict__ x, const float* __restrict__ h0,
                            short* __restrict__ xb, short* __restrict__ hb0) {
  const long NX4 = (long)NB * NT * NCAT / 4;  // 8388608
  const long NH4 = (long)NB * NHID / 4;       // 16384
  long i = (long)blockIdx.x * blockDim.x + threadIdx.x;
  long stride = (long)gridDim.x * blockDim.x;
  for (long j = i; j < NX4 + NH4; j += stride) {
    if (j < NH4) {
      float4v v = ((const float4v*)h0)[j];
      short4v s; s[0]=f2bf(v[0]); s[1]=f2bf(v[1]); s[2]=f2bf(v[2]); s[3]=f2bf(v[3]);
      ((short4v*)hb0)[j] = s;
    } else {
      long jj = j - NH4;
      float4v v = ((const float4v*)x)[jj];
      short4v s; s[0]=f2bf(v[0]); s[1]=f2bf(v[1]); s[2]=f2bf(v[2]); s[3]=f2bf(v[3]);
      ((short4v*)xb)[jj] = s;
    }
  }
}

// Persistent GRU kernel. 64 wgs x 256 threads. wg w owns h-columns [w*16, w*16+16).
// LDS: B-fragments of [Uz|Wz ; Uh|Wh] slice, 64 kb x 2 nt x 64 lanes x 16B = 128 KB.
__global__ __launch_bounds__(256, 1) void gru_kernel(
    const float* __restrict__ h0, const float* __restrict__ Wh, const float* __restrict__ Wz,
    const float* __restrict__ Uh, const float* __restrict__ Uz, const float* __restrict__ bz,
    const float* __restrict__ Wout, const short* __restrict__ xb,
    short* __restrict__ hbuf0, short* __restrict__ hbuf1,
    unsigned* __restrict__ bar, float* __restrict__ out)
{
  extern __shared__ char smem[];
  short8v* ufr = (short8v*)smem;  // [(kb*2+nt)*64 + lane]

  const int tid  = threadIdx.x;
  const int wg   = blockIdx.x;
  const int lane = tid & 63;
  const int wm   = tid >> 6;     // wave id = m-tile (batch rows 16*wm..16*wm+15)
  const int col  = lane & 15;
  const int quad = lane >> 4;
  const int jg   = wg * 16 + col;  // this lane's h/gate column

  // ---- one-time: fill LDS with weight B-fragments (bf16, fragment order) ----
  for (int idx = tid; idx < 64 * 2 * 64; idx += 256) {
    int l  = idx & 63;
    int nt = (idx >> 6) & 1;          // 0 = z-gate, 1 = h-gate
    int kb = idx >> 7;                // k-block (32 wide)
    int j  = wg * 16 + (l & 15);      // weight row (gate column)
    int k0 = kb * 32 + (l >> 4) * 8;
    const float* Us = nt ? Uh : Uz;
    const float* Ws = nt ? Wh : Wz;
    short8v v;
#pragma unroll
    for (int e = 0; e < 8; ++e) {
      int k = k0 + e;
      float f = (k < NHID) ? Us[j * NHID + k] : Ws[j * NCAT + (k - NHID)];
      v[e] = f2bf(f);
    }
    ufr[idx] = v;
  }
  __syncthreads();

  // ---- persistent per-lane state ----
  const int arow = wm * 16 + col;   // A-frag batch row (A layout: m = lane&15)
  const int kq   = quad * 8;        // A/B frag k-offset within k-block
  const float bzv = bz[jg];
  float hl[4];                      // fp32 h state for rows (wm*16+quad*4+r, col jg)
#pragma unroll
  for (int r = 0; r < 4; ++r) hl[r] = h0[(wm * 16 + quad * 4 + r) * NHID + jg];

  short* hb[2] = { hbuf0, hbuf1 };

  for (int t = 0; t < NT; ++t) {
    const short* hc = hb[t & 1];
    short*       hn = hb[(t + 1) & 1];
    f32x4 accz = {0.f, 0.f, 0.f, 0.f};
    f32x4 acch = {0.f, 0.f, 0.f, 0.f};
    const short* hrow = hc + arow * NHID + kq;
    const short* xrow = xb + ((long)(arow * NT + t)) * NCAT + kq;

#pragma unroll 8
    for (int kb = 0; kb < 32; ++kb) {       // K-half 1: h @ [Uz;Uh]
      short8v a = *(const short8v*)(hrow + kb * 32);
      accz = __builtin_amdgcn_mfma_f32_16x16x32_bf16(a, ufr[kb * 128 + lane],      accz, 0, 0, 0);
      acch = __builtin_amdgcn_mfma_f32_16x16x32_bf16(a, ufr[kb * 128 + 64 + lane], acch, 0, 0, 0);
    }
#pragma unroll 8
    for (int kb = 32; kb < 64; ++kb) {      // K-half 2: x_t @ [Wz;Wh]
      short8v a = *(const short8v*)(xrow + (kb - 32) * 32);
      accz = __builtin_amdgcn_mfma_f32_16x16x32_bf16(a, ufr[kb * 128 + lane],      accz, 0, 0, 0);
      acch = __builtin_amdgcn_mfma_f32_16x16x32_bf16(a, ufr[kb * 128 + 64 + lane], acch, 0, 0, 0);
    }

    // epilogue: gates in fp32, update register-resident h, publish bf16 copy
#pragma unroll
    for (int r = 0; r < 4; ++r) {
      float zp = accz[r] + bzv;
      float z  = 1.f / (1.f + __expf(-zp));
      float ht = tanhf(acch[r]);
      float v  = hl[r] + z * (ht - hl[r]);
      hl[r] = v;
      hn[(wm * 16 + quad * 4 + r) * NHID + jg] = f2bf(v);
    }

    // ---- device-wide barrier (release h stores -> all wgs -> acquire) ----
    __syncthreads();                 // drains this wg's stores (vmcnt(0) before s_barrier)
    if (tid == 0) {
      __threadfence();               // agent release: flush to coherence point
      unsigned g = __hip_atomic_load(bar + 64, __ATOMIC_RELAXED, __HIP_MEMORY_SCOPE_AGENT);
      unsigned a = __hip_atomic_fetch_add(bar, 1u, __ATOMIC_ACQ_REL, __HIP_MEMORY_SCOPE_AGENT);
      if (a == NWG - 1) {
        __hip_atomic_store(bar, 0u, __ATOMIC_RELAXED, __HIP_MEMORY_SCOPE_AGENT);
        __hip_atomic_fetch_add(bar + 64, 1u, __ATOMIC_RELEASE, __HIP_MEMORY_SCOPE_AGENT);
      } else {
        while (__hip_atomic_load(bar + 64, __ATOMIC_ACQUIRE, __HIP_MEMORY_SCOPE_AGENT) == g) {
          __builtin_amdgcn_s_sleep(1);
        }
      }
      __threadfence();               // agent acquire: invalidate stale cached h
    }
    __syncthreads();
  }

  // ---- final: out[b, c] = sum_k hT[b,k] * Wout[c,k]; hT = hb[0] ----
  {
    const short* hT = hb[0];
    f32x4 acc = {0.f, 0.f, 0.f, 0.f};
    const short* hrow2 = hT + arow * NHID + kq;
    const float* wrow  = Wout + (long)jg * NHID + kq;
#pragma unroll 4
    for (int kb = 0; kb < 32; ++kb) {
      short8v a = *(const short8v*)(hrow2 + kb * 32);
      float4v w0 = *(const float4v*)(wrow + kb * 32);
      float4v w1 = *(const float4v*)(wrow + kb * 32 + 4);
      short8v b;
      b[0] = f2bf(w0[0]); b[1] = f2bf(w0[1]); b[2] = f2bf(w0[2]); b[3] = f2bf(w0[3]);
      b[4] = f2bf(w1[0]); b[5] = f2bf(w1[1]); b[6] = f2bf(w1[2]); b[7] = f2bf(w1[3]);
      acc = __builtin_amdgcn_mfma_f32_16x16x32_bf16(a, b, acc, 0, 0, 0);
    }
#pragma unroll
    for (int r = 0; r < 4; ++r)
      out[(wm * 16 + quad * 4 + r) * NCAT + jg] = acc[r];
  }
}

extern "C" void kernel_launch(void* const* d_in, const int* in_sizes, int n_in,
                              void* d_out, int out_size, void* d_ws, size_t ws_size,
                              hipStream_t stream) {
  const float* x    = (const float*)d_in[0];
  const float* h0   = (const float*)d_in[1];
  const float* Wh   = (const float*)d_in[2];
  const float* Wz   = (const float*)d_in[3];
  const float* Uh   = (const float*)d_in[5];
  const float* Uz   = (const float*)d_in[6];
  const float* bz   = (const float*)d_in[8];
  const float* Wout = (const float*)d_in[10];

  char* ws = (char*)d_ws;
  // layout: [0,512) barrier | [512, 512+128K) hbuf0 | next 128K hbuf1 | xb bf16 64MB
  unsigned* bar = (unsigned*)ws;
  short* hb0 = (short*)(ws + 512);
  short* hb1 = (short*)(ws + 512 + 131072);
  short* xb  = (short*)(ws + 512 + 262144);
  // total workspace needed: 512 + 256KB + 64MB ~= 64.3 MiB

  hipMemsetAsync(bar, 0, 512, stream);
  cast_kernel<<<4096, 256, 0, stream>>>(x, h0, xb, hb0);

  hipFuncSetAttribute((const void*)gru_kernel,
                      hipFuncAttributeMaxDynamicSharedMemorySize, 131072);
  gru_kernel<<<NWG, 256, 131072, stream>>>(h0, Wh, Wz, Uh, Uz, bz, Wout, xb,
                                           hb0, hb1, bar, (float*)d_out);
}

// Round 2
// 7648.716 us; speedup vs baseline: 1.1785x; 1.1785x over previous
//
#include <hip/hip_runtime.h>

typedef __attribute__((ext_vector_type(8))) short short8v;
typedef __attribute__((ext_vector_type(4))) short short4v;
typedef __attribute__((ext_vector_type(4))) float f32x4;
typedef __attribute__((ext_vector_type(4))) float float4v;

#define NHID 1024
#define NCAT 1024
#define NB   64
#define NT   512
#define NWG  64

__device__ __forceinline__ short f2bf(float f) {
  union { float f; unsigned u; } c; c.f = f;
  unsigned r = (c.u + 0x7fffu + ((c.u >> 16) & 1u)) >> 16;
  return (short)r;
}

__global__ void cast_kernel(const float* __restrict__ x, const float* __restrict__ h0,
                            short* __restrict__ xb, short* __restrict__ hb0) {
  const long NX4 = (long)NB * NT * NCAT / 4;
  const long NH4 = (long)NB * NHID / 4;
  long i = (long)blockIdx.x * blockDim.x + threadIdx.x;
  long stride = (long)gridDim.x * blockDim.x;
  for (long j = i; j < NX4 + NH4; j += stride) {
    if (j < NH4) {
      float4v v = ((const float4v*)h0)[j];
      short4v s; s[0]=f2bf(v[0]); s[1]=f2bf(v[1]); s[2]=f2bf(v[2]); s[3]=f2bf(v[3]);
      ((short4v*)hb0)[j] = s;
    } else {
      long jj = j - NH4;
      float4v v = ((const float4v*)x)[jj];
      short4v s; s[0]=f2bf(v[0]); s[1]=f2bf(v[1]); s[2]=f2bf(v[2]); s[3]=f2bf(v[3]);
      ((short4v*)xb)[jj] = s;
    }
  }
}

// 64 persistent wgs x 256 threads. wg owns 16 h-columns. Waves split K:
// wave 0: k[0,512) of h-half; wave 1: k[512,1024) of h-half;
// wave 2: k[0,512) of x-half; wave 3: k[512,1024) of x-half.
// Each wave computes partials for ALL 4 m-tiles (batch row blocks) x both gates,
// so every LDS B-fragment is read exactly once per step per CU.
// Cross-wave reduce via LDS, epilogue owner = wave wm (m-tile wm).
// Sync: per-wave flag (value = produced step), write-through h stores,
// relaxed wave-parallel poll + one acquire fence. No device barrier object.
__global__ __launch_bounds__(256, 1) void gru_kernel(
    const float* __restrict__ h0, const float* __restrict__ Wh, const float* __restrict__ Wz,
    const float* __restrict__ Uh, const float* __restrict__ Uz, const float* __restrict__ bz,
    const float* __restrict__ Wout, const short* __restrict__ xb,
    short* __restrict__ hbuf0, short* __restrict__ hbuf1,
    unsigned* __restrict__ flags, float* __restrict__ out)
{
  extern __shared__ char smem[];
  short8v* ufr = (short8v*)smem;               // [(kb*2+gate)*64 + lane], 128 KB
  float*   red = (float*)(smem + 131072);      // reduce slots, 24 KB

  const int tid  = threadIdx.x;
  const int wg   = blockIdx.x;
  const int lane = tid & 63;
  const int wm   = tid >> 6;        // wave id: 0..3
  const int col  = lane & 15;
  const int quad = lane >> 4;
  const int jg   = wg * 16 + col;   // owned h/gate column
  const int kq   = quad * 8;

  // ---- one-time: weight B-fragments into LDS ----
  for (int idx = tid; idx < 64 * 2 * 64; idx += 256) {
    int l  = idx & 63;
    int nt = (idx >> 6) & 1;
    int kb = idx >> 7;
    int j  = wg * 16 + (l & 15);
    int k0 = kb * 32 + (l >> 4) * 8;
    const float* Us = nt ? Uh : Uz;
    const float* Ws = nt ? Wh : Wz;
    short8v v;
#pragma unroll
    for (int e = 0; e < 8; ++e) {
      int k = k0 + e;
      float f = (k < NHID) ? Us[j * NHID + k] : Ws[j * NCAT + (k - NHID)];
      v[e] = f2bf(f);
    }
    ufr[idx] = v;
  }
  __syncthreads();

  const float bzv = bz[jg];
  float hl[4];
#pragma unroll
  for (int r = 0; r < 4; ++r) hl[r] = h0[(wm * 16 + quad * 4 + r) * NHID + jg];

  short* hb[2] = { hbuf0, hbuf1 };
  const int  kb0       = wm * 16;          // this wave's k-quarter (kb units of 32)
  const bool is_h_wave = (wm < 2);
  unsigned* myflag = flags + wg * 4 + wm;
  const unsigned long long* fp64 = ((const unsigned long long*)flags) + lane * 2;

  for (int t = 0; t < NT; ++t) {
    f32x4 pz[4], ph[4];
#pragma unroll
    for (int mt = 0; mt < 4; ++mt) {
      pz[mt] = (f32x4){0.f,0.f,0.f,0.f};
      ph[mt] = (f32x4){0.f,0.f,0.f,0.f};
    }

    if (is_h_wave) {
      if (t > 0) {
        const unsigned tt = (unsigned)t;
        for (;;) {
          unsigned long long v0 = __hip_atomic_load(fp64 + 0, __ATOMIC_RELAXED, __HIP_MEMORY_SCOPE_AGENT);
          unsigned long long v1 = __hip_atomic_load(fp64 + 1, __ATOMIC_RELAXED, __HIP_MEMORY_SCOPE_AGENT);
          unsigned a0 = (unsigned)v0, a1 = (unsigned)(v0 >> 32);
          unsigned a2 = (unsigned)v1, a3 = (unsigned)(v1 >> 32);
          unsigned mn = min(min(a0, a1), min(a2, a3));
          if (__ballot(mn < tt) == 0ull) break;
          __builtin_amdgcn_s_sleep(1);
        }
        __builtin_amdgcn_fence(__ATOMIC_ACQUIRE, "agent");
      }
      const short* hc = hb[t & 1];
#pragma unroll 4
      for (int i = 0; i < 16; ++i) {
        int kb = kb0 + i;
        short8v bz_ = ufr[kb * 128 + lane];
        short8v bh_ = ufr[kb * 128 + 64 + lane];
#pragma unroll
        for (int mt = 0; mt < 4; ++mt) {
          short8v a = *(const short8v*)(hc + (mt * 16 + col) * NHID + kb * 32 + kq);
          pz[mt] = __builtin_amdgcn_mfma_f32_16x16x32_bf16(a, bz_, pz[mt], 0, 0, 0);
          ph[mt] = __builtin_amdgcn_mfma_f32_16x16x32_bf16(a, bh_, ph[mt], 0, 0, 0);
        }
      }
    } else {
#pragma unroll 4
      for (int i = 0; i < 16; ++i) {
        int kb = kb0 + i;                       // 32..63
        int xk = (kb - 32) * 32 + kq;
        short8v bz_ = ufr[kb * 128 + lane];
        short8v bh_ = ufr[kb * 128 + 64 + lane];
#pragma unroll
        for (int mt = 0; mt < 4; ++mt) {
          short8v a = *(const short8v*)(xb + ((long)(mt * 16 + col) * NT + t) * NCAT + xk);
          pz[mt] = __builtin_amdgcn_mfma_f32_16x16x32_bf16(a, bz_, pz[mt], 0, 0, 0);
          ph[mt] = __builtin_amdgcn_mfma_f32_16x16x32_bf16(a, bh_, ph[mt], 0, 0, 0);
        }
      }
    }

    // ---- cross-wave reduce: write partials for other m-tiles ----
#pragma unroll
    for (int mt = 0; mt < 4; ++mt) {
      if (mt == wm) continue;
      int s = (wm < mt) ? wm : wm - 1;
      float* sl = red + (((mt * 3 + s) * 64) + lane) * 8;
      *(f32x4*)sl       = pz[mt];
      *(f32x4*)(sl + 4) = ph[mt];
    }
    __syncthreads();

    f32x4 accz = pz[wm], acch = ph[wm];
#pragma unroll
    for (int s = 0; s < 3; ++s) {
      const float* sl = red + (((wm * 3 + s) * 64) + lane) * 8;
      accz += *(const f32x4*)sl;
      acch += *(const f32x4*)(sl + 4);
    }

    // ---- epilogue (own m-tile): gates fp32, update h, publish bf16 write-through ----
    short* hn = hb[(t + 1) & 1];
#pragma unroll
    for (int r = 0; r < 4; ++r) {
      float zp = accz[r] + bzv;
      float z  = 1.f / (1.f + __expf(-zp));
      float ht = tanhf(acch[r]);
      float v  = hl[r] + z * (ht - hl[r]);
      hl[r] = v;
      __hip_atomic_store((unsigned short*)&hn[(wm * 16 + quad * 4 + r) * NHID + jg],
                         (unsigned short)f2bf(v), __ATOMIC_RELAXED, __HIP_MEMORY_SCOPE_AGENT);
    }
    asm volatile("s_waitcnt vmcnt(0)" ::: "memory");   // h stores reached coherence point
    __hip_atomic_store(myflag, (unsigned)(t + 1), __ATOMIC_RELAXED, __HIP_MEMORY_SCOPE_AGENT);
    __syncthreads();   // protect reduce slots for next iteration
  }

  // ---- out = hT @ Wout.T, hT = hb[0] (h_512). Wave wm handles its m-tile rows ----
  {
    const unsigned* fo = flags + lane * 4 + wm;
    for (;;) {
      unsigned v = __hip_atomic_load(fo, __ATOMIC_RELAXED, __HIP_MEMORY_SCOPE_AGENT);
      if (__ballot(v < (unsigned)NT) == 0ull) break;
      __builtin_amdgcn_s_sleep(1);
    }
    __builtin_amdgcn_fence(__ATOMIC_ACQUIRE, "agent");

    const short* hT = hb[0];
    f32x4 acc = {0.f, 0.f, 0.f, 0.f};
    const short* hrow2 = hT + (wm * 16 + col) * NHID + kq;
    const float* wrow  = Wout + (long)jg * NHID + kq;
#pragma unroll 4
    for (int kb = 0; kb < 32; ++kb) {
      short8v a = *(const short8v*)(hrow2 + kb * 32);
      float4v w0 = *(const float4v*)(wrow + kb * 32);
      float4v w1 = *(const float4v*)(wrow + kb * 32 + 4);
      short8v b;
      b[0] = f2bf(w0[0]); b[1] = f2bf(w0[1]); b[2] = f2bf(w0[2]); b[3] = f2bf(w0[3]);
      b[4] = f2bf(w1[0]); b[5] = f2bf(w1[1]); b[6] = f2bf(w1[2]); b[7] = f2bf(w1[3]);
      acc = __builtin_amdgcn_mfma_f32_16x16x32_bf16(a, b, acc, 0, 0, 0);
    }
#pragma unroll
    for (int r = 0; r < 4; ++r)
      out[(wm * 16 + quad * 4 + r) * NCAT + jg] = acc[r];
  }
}

extern "C" void kernel_launch(void* const* d_in, const int* in_sizes, int n_in,
                              void* d_out, int out_size, void* d_ws, size_t ws_size,
                              hipStream_t stream) {
  const float* x    = (const float*)d_in[0];
  const float* h0   = (const float*)d_in[1];
  const float* Wh   = (const float*)d_in[2];
  const float* Wz   = (const float*)d_in[3];
  const float* Uh   = (const float*)d_in[5];
  const float* Uz   = (const float*)d_in[6];
  const float* bz   = (const float*)d_in[8];
  const float* Wout = (const float*)d_in[10];

  char* ws = (char*)d_ws;
  // layout: flags [0,1024) | hb0 128K | hb1 128K | xb bf16 64MB
  unsigned* flags = (unsigned*)ws;
  short* hb0 = (short*)(ws + 1024);
  short* hb1 = (short*)(ws + 1024 + 131072);
  short* xb  = (short*)(ws + 1024 + 262144);

  hipMemsetAsync(flags, 0, 1024, stream);
  cast_kernel<<<4096, 256, 0, stream>>>(x, h0, xb, hb0);

  hipFuncSetAttribute((const void*)gru_kernel,
                      hipFuncAttributeMaxDynamicSharedMemorySize, 155648);
  gru_kernel<<<NWG, 256, 155648, stream>>>(h0, Wh, Wz, Uh, Uz, bz, Wout, xb,
                                           hb0, hb1, flags, (float*)d_out);
}